// Round 10
// baseline (162.101 us; speedup 1.0000x reference)
//
#include <hip/hip_runtime.h>
#include <math.h>

#define BB 4
#define NN 1024
#define CC 1024
#define HH 16
#define DD 64
#define N3 3072

typedef __attribute__((ext_vector_type(8))) short bf16x8;
typedef __attribute__((ext_vector_type(8))) _Float16 f16x8;
typedef __attribute__((ext_vector_type(4))) _Float16 f16x4;
typedef __attribute__((ext_vector_type(4))) float f32x4;
typedef __attribute__((ext_vector_type(4))) unsigned int u32x4;
typedef __attribute__((ext_vector_type(2))) unsigned int u32x2;

struct ushort4_t { unsigned short x, y, z, w; };

static __device__ __forceinline__ unsigned short f2b(float f) {
    union { float f; unsigned int u; } v; v.f = f;
    unsigned int r = (v.u + 0x7fffu + ((v.u >> 16) & 1u)) >> 16;  // RNE
    return (unsigned short)r;
}

// async global->LDS, 16B per lane
static __device__ __forceinline__ void ldg_lds16(const void* g, void* l) {
    __builtin_amdgcn_global_load_lds(
        (const __attribute__((address_space(1))) unsigned int*)g,
        (__attribute__((address_space(3))) unsigned int*)l, 16, 0, 0);
}

// raw barrier / counted waits (asm so the compiler cannot auto-drain vmcnt)
static __device__ __forceinline__ void barx()  { asm volatile("s_barrier" ::: "memory"); }
static __device__ __forceinline__ void wlg0()  { asm volatile("s_waitcnt lgkmcnt(0)" ::: "memory");
                                                 __builtin_amdgcn_sched_barrier(0); }
static __device__ __forceinline__ void wvm8()  { asm volatile("s_waitcnt vmcnt(8)" ::: "memory"); }
static __device__ __forceinline__ void wvm4()  { asm volatile("s_waitcnt vmcnt(4)" ::: "memory"); }
static __device__ __forceinline__ void wvm2()  { asm volatile("s_waitcnt vmcnt(2)" ::: "memory"); }
static __device__ __forceinline__ void wvm0()  { asm volatile("s_waitcnt vmcnt(0)" ::: "memory"); }
static __device__ __forceinline__ void wnone() {}

// ---------------------------------------------------------------------------
// prep: input conversion (unchanged).
// ---------------------------------------------------------------------------
__global__ __launch_bounds__(256) void prep(const float* __restrict__ x,
                                            const float* __restrict__ wq,
                                            const float* __restrict__ wp,
                                            _Float16* __restrict__ Xh,
                                            _Float16* __restrict__ Wqt,
                                            _Float16* __restrict__ Wpt,
                                            float* __restrict__ ct,
                                            float* __restrict__ st) {
    __shared__ __align__(16) _Float16 T[64][72];   // pad 64->72 shorts
    const int blk = blockIdx.x;
    const int t = threadIdx.x;
    if (blk < 4096) {
        int tid = blk * 256 + t;
        float4 v = ((const float4*)x)[tid];
        f16x4 o = {(_Float16)v.x, (_Float16)v.y, (_Float16)v.z, (_Float16)v.w};
        ((f16x4*)Xh)[tid] = o;
    } else if (blk < 5120) {
        const float* src; _Float16* dst; int ns, k0, n0;
        if (blk < 4864) {
            int idx = blk - 4096;
            k0 = (idx & 15) * 64; n0 = (idx >> 4) * 64;
            src = wq; dst = Wqt; ns = N3;
        } else {
            int idx = blk - 4864;
            k0 = (idx & 15) * 64; n0 = (idx >> 4) * 64;
            src = wp; dst = Wpt; ns = 1024;
        }
        {
            const int r  = t >> 2;
            const int cf = (t & 3) * 16;
            const float* sp = src + (size_t)(k0 + r) * ns + n0 + cf;
            float4 v0 = *(const float4*)(sp);
            float4 v1 = *(const float4*)(sp + 4);
            float4 v2 = *(const float4*)(sp + 8);
            float4 v3 = *(const float4*)(sp + 12);
            f16x8 a, b;
            a[0]=(_Float16)v0.x; a[1]=(_Float16)v0.y; a[2]=(_Float16)v0.z; a[3]=(_Float16)v0.w;
            a[4]=(_Float16)v1.x; a[5]=(_Float16)v1.y; a[6]=(_Float16)v1.z; a[7]=(_Float16)v1.w;
            b[0]=(_Float16)v2.x; b[1]=(_Float16)v2.y; b[2]=(_Float16)v2.z; b[3]=(_Float16)v2.w;
            b[4]=(_Float16)v3.x; b[5]=(_Float16)v3.y; b[6]=(_Float16)v3.z; b[7]=(_Float16)v3.w;
            *(f16x8*)&T[r][cf]     = a;
            *(f16x8*)&T[r][cf + 8] = b;
        }
        __syncthreads();
        {
            const int n  = t >> 2;
            const int kc = t & 3;
            f16x8 o0, o1;
            #pragma unroll
            for (int kk = 0; kk < 8; kk++) o0[kk] = T[kc * 16 + kk][n];
            #pragma unroll
            for (int kk = 0; kk < 8; kk++) o1[kk] = T[kc * 16 + 8 + kk][n];
            _Float16* dp = dst + (size_t)(n0 + n) * 1024 + k0 + kc * 16;
            *(f16x8*)dp       = o0;
            *(f16x8*)(dp + 8) = o1;
        }
    } else {
        int tid = (blk - 5120) * 256 + t;  // 32768
        int n = tid >> 5, i = tid & 31;
        double ang = (double)n * exp2(-(double)i * (13.287712379549449 / 32.0));
        ct[tid] = (float)cos(ang);
        st[tid] = (float)sin(ang);
    }
}

// ---------------------------------------------------------------------------
// QKV GEMM: 256x256 deep-pipelined body + LDS-transpose epilogue (R3 variant,
// best measured 42.96 us; unchanged from R9).
// ---------------------------------------------------------------------------
__global__ __launch_bounds__(512, 2) void qkv_mfma(const _Float16* __restrict__ Ah,
                                                   const _Float16* __restrict__ Bt,
                                                   const float* __restrict__ bias,
                                                   const float* __restrict__ cost,
                                                   const float* __restrict__ sint,
                                                   unsigned short* __restrict__ Q,
                                                   unsigned short* __restrict__ K,
                                                   unsigned short* __restrict__ Vtg) {
    __shared__ __align__(16) _Float16 LA[4][128 * 64];
    __shared__ __align__(16) _Float16 LB[4][128 * 64];

    const int t    = threadIdx.x;
    const int lane = t & 63;
    const int w    = t >> 6;
    const int ln   = lane & 15, qd = lane >> 4;
    const int n0   = blockIdx.x * 256;
    const int m0   = blockIdx.y * 256;
    const int wm   = (w >> 2) * 128;
    const int wn   = (w & 3) * 64;

    const int L0 = t >> 3, hc0 = (t & 7) ^ (L0 & 7);
    const int row0 = 2 * L0 + (hc0 >> 2), co0 = (hc0 & 3) * 16;
    const int pp = 512 + t;
    const int L1 = pp >> 3, hc1 = (pp & 7) ^ (L1 & 7);
    const int row1 = 2 * L1 + (hc1 >> 2), co1 = (hc1 & 3) * 16;

    const char* gA = (const char*)Ah;
    const char* gB = (const char*)Bt;
    const size_t aof0 = (size_t)(m0 + row0) * 2048 + co0;
    const size_t aof1 = (size_t)(m0 + row1) * 2048 + co1;
    const size_t bof0 = (size_t)(n0 + row0) * 2048 + co0;
    const size_t bof1 = (size_t)(n0 + row1) * 2048 + co1;
    const int ld0 = (w * 64) * 8;
    const int ld1 = (512 + w * 64) * 8;

#define STAGE_A(kk, SLOT) { ldg_lds16(gA + aof0 + (size_t)(kk) * 64, &LA[SLOT][ld0]); \
                            ldg_lds16(gA + aof1 + (size_t)(kk) * 64, &LA[SLOT][ld1]); }
#define STAGE_B(kk, SLOT) { ldg_lds16(gB + bof0 + (size_t)(kk) * 64, &LB[SLOT][ld0]); \
                            ldg_lds16(gB + bof1 + (size_t)(kk) * 64, &LB[SLOT][ld1]); }

    STAGE_A(0, 0); STAGE_B(0, 0);
    STAGE_A(1, 1); STAGE_B(1, 1);
    STAGE_A(2, 2); STAGE_B(2, 2);
    wvm8();
    barx();

    f32x4 acc[8][4];
    #pragma unroll
    for (int i = 0; i < 8; i++)
        #pragma unroll
        for (int j = 0; j < 4; j++) acc[i][j] = (f32x4){0.f, 0.f, 0.f, 0.f};

    auto frag = [&](const _Float16* Lb, int r, int c) -> f16x8 {
        int idx = ((r >> 1) << 6) + ((((((r & 1) << 2) | c)) ^ ((r >> 1) & 7)) << 3);
        return *(const f16x8*)&Lb[idx];
    };

#define QK_TILE(kk, SLOT, STG, WAITFN) {                                            \
    const _Float16* Ab = LA[SLOT];                                                  \
    const _Float16* Bb = LB[SLOT];                                                  \
    f16x8 af[4], bf[4];                                                             \
    _Pragma("unroll") for (int i = 0; i < 4; i++) af[i] = frag(Ab, wm + i * 16 + ln, qd); \
    _Pragma("unroll") for (int j = 0; j < 4; j++) bf[j] = frag(Bb, wn + j * 16 + ln, qd); \
    if (STG) STAGE_A((kk) + 3, ((kk) + 3) & 3);                                     \
    barx(); wlg0();                                                                 \
    __builtin_amdgcn_s_setprio(1);                                                  \
    _Pragma("unroll") for (int i = 0; i < 4; i++)                                   \
        _Pragma("unroll") for (int j = 0; j < 4; j++)                               \
            acc[i][j] = __builtin_amdgcn_mfma_f32_16x16x32_f16(af[i], bf[j], acc[i][j], 0, 0, 0); \
    __builtin_amdgcn_s_setprio(0);                                                  \
    barx();                                                                         \
    _Pragma("unroll") for (int i = 0; i < 4; i++) af[i] = frag(Ab, wm + 64 + i * 16 + ln, qd); \
    if (STG) STAGE_B((kk) + 3, ((kk) + 3) & 3);                                     \
    WAITFN();                                                                       \
    barx(); wlg0();                                                                 \
    __builtin_amdgcn_s_setprio(1);                                                  \
    _Pragma("unroll") for (int i = 0; i < 4; i++)                                   \
        _Pragma("unroll") for (int j = 0; j < 4; j++)                               \
            acc[4 + i][j] = __builtin_amdgcn_mfma_f32_16x16x32_f16(af[i], bf[j], acc[4 + i][j], 0, 0, 0); \
    __builtin_amdgcn_s_setprio(0);                                                  \
    barx();                                                                         \
}

    for (int k = 0; k < 28; k += 4) {
        QK_TILE(k + 0, 0, 1, wvm8);
        QK_TILE(k + 1, 1, 1, wvm8);
        QK_TILE(k + 2, 2, 1, wvm8);
        QK_TILE(k + 3, 3, 1, wvm8);
    }
    QK_TILE(28, 0, 1, wvm8);   // stages tile 31
    QK_TILE(29, 1, 0, wvm4);
    QK_TILE(30, 2, 0, wvm0);
    QK_TILE(31, 3, 0, wnone);

#undef QK_TILE
#undef STAGE_A
#undef STAGE_B

    float* LW = (float*)(&LA[0][0]) + w * (16 * 68);
    const int s = (n0 + wn) >> 10;
    const int h = ((n0 + wn) >> 6) & 15;
    const int erow = lane >> 2;
    const int ec0  = (lane & 3) * 16;

    if (s < 2) {
        unsigned short* dst = (s == 0) ? Q : K;
        const float sc0 = (s == 0) ? 0.125f : 1.0f;
        f32x4 bb0 = *(const f32x4*)&bias[n0 + wn + ec0 + 0];
        f32x4 bb1 = *(const f32x4*)&bias[n0 + wn + ec0 + 4];
        f32x4 bb2 = *(const f32x4*)&bias[n0 + wn + ec0 + 8];
        f32x4 bb3 = *(const f32x4*)&bias[n0 + wn + ec0 + 12];
        #pragma unroll
        for (int i = 0; i < 8; i++) {
            #pragma unroll
            for (int j = 0; j < 4; j++)
                #pragma unroll
                for (int reg = 0; reg < 4; reg++)
                    LW[(qd * 4 + reg) * 68 + j * 16 + ln] = acc[i][j][reg];
            wlg0();
            f32x4 v0 = *(const f32x4*)&LW[erow * 68 + ec0 + 0];
            f32x4 v1 = *(const f32x4*)&LW[erow * 68 + ec0 + 4];
            f32x4 v2 = *(const f32x4*)&LW[erow * 68 + ec0 + 8];
            f32x4 v3 = *(const f32x4*)&LW[erow * 68 + ec0 + 12];
            wlg0();
            int row = m0 + wm + i * 16 + erow;
            int b = row >> 10, n = row & 1023;
            f32x4 cs0 = *(const f32x4*)&cost[n * 32 + (ec0 >> 1)];
            f32x4 cs1 = *(const f32x4*)&cost[n * 32 + (ec0 >> 1) + 4];
            f32x4 sn0 = *(const f32x4*)&sint[n * 32 + (ec0 >> 1)];
            f32x4 sn1 = *(const f32x4*)&sint[n * 32 + (ec0 >> 1) + 4];
            cs0 *= sc0; cs1 *= sc0; sn0 *= sc0; sn1 *= sc0;
            v0 += bb0; v1 += bb1; v2 += bb2; v3 += bb3;
            unsigned int pk0, pk1, pk2, pk3, pk4, pk5, pk6, pk7;
#define RP(PK, ve, vo, cs, sn) { float oe = (ve) * (cs) - (vo) * (sn);              \
                                 float oo = (vo) * (cs) + (ve) * (sn);              \
            asm("v_cvt_pk_bf16_f32 %0, %1, %2" : "=v"(PK) : "v"(oe), "v"(oo)); }
            RP(pk0, v0[0], v0[1], cs0[0], sn0[0]);
            RP(pk1, v0[2], v0[3], cs0[1], sn0[1]);
            RP(pk2, v1[0], v1[1], cs0[2], sn0[2]);
            RP(pk3, v1[2], v1[3], cs0[3], sn0[3]);
            RP(pk4, v2[0], v2[1], cs1[0], sn1[0]);
            RP(pk5, v2[2], v2[3], cs1[1], sn1[1]);
            RP(pk6, v3[0], v3[1], cs1[2], sn1[2]);
            RP(pk7, v3[2], v3[3], cs1[3], sn1[3]);
#undef RP
            unsigned short* op = dst + (((size_t)(b * HH + h)) * NN + n) * DD + ec0;
            u32x4 o0; o0[0] = pk0; o0[1] = pk1; o0[2] = pk2; o0[3] = pk3;
            u32x4 o1; o1[0] = pk4; o1[1] = pk5; o1[2] = pk6; o1[3] = pk7;
            *(u32x4*)op = o0;
            *(u32x4*)(op + 8) = o1;
        }
    } else {
        const float bb = bias[n0 + wn + lane];
        #pragma unroll
        for (int i = 0; i < 8; i++) {
            #pragma unroll
            for (int j = 0; j < 4; j++)
                #pragma unroll
                for (int reg = 0; reg < 4; reg++)
                    LW[(qd * 4 + reg) * 68 + j * 16 + ln] = acc[i][j][reg];
            wlg0();
            float e0  = LW[ 0 * 68 + lane] + bb, e1  = LW[ 1 * 68 + lane] + bb;
            float e2  = LW[ 2 * 68 + lane] + bb, e3  = LW[ 3 * 68 + lane] + bb;
            float e4  = LW[ 4 * 68 + lane] + bb, e5  = LW[ 5 * 68 + lane] + bb;
            float e6  = LW[ 6 * 68 + lane] + bb, e7  = LW[ 7 * 68 + lane] + bb;
            float e8  = LW[ 8 * 68 + lane] + bb, e9  = LW[ 9 * 68 + lane] + bb;
            float e10 = LW[10 * 68 + lane] + bb, e11 = LW[11 * 68 + lane] + bb;
            float e12 = LW[12 * 68 + lane] + bb, e13 = LW[13 * 68 + lane] + bb;
            float e14 = LW[14 * 68 + lane] + bb, e15 = LW[15 * 68 + lane] + bb;
            wlg0();
            unsigned int pk0, pk1, pk2, pk3, pk4, pk5, pk6, pk7;
#define CV(PK, a, b_) asm("v_cvt_pk_bf16_f32 %0, %1, %2" : "=v"(PK) : "v"(a), "v"(b_))
            CV(pk0, e0,  e1);  CV(pk1, e2,  e3);
            CV(pk2, e4,  e5);  CV(pk3, e6,  e7);
            CV(pk4, e8,  e9);  CV(pk5, e10, e11);
            CV(pk6, e12, e13); CV(pk7, e14, e15);
#undef CV
            int row0v = m0 + wm + i * 16;
            int b = row0v >> 10, nn = row0v & 1023;
            unsigned short* vp = Vtg + ((size_t)(b * HH + h) * DD + lane) * NN + nn;
            u32x4 o0; o0[0] = pk0; o0[1] = pk1; o0[2] = pk2; o0[3] = pk3;
            u32x4 o1; o1[0] = pk4; o1[1] = pk5; o1[2] = pk6; o1[3] = pk7;
            *(u32x4*)vp = o0;
            *(u32x4*)(vp + 8) = o1;
        }
    }
}

// ---------------------------------------------------------------------------
// Flash attention v8: S-ahead pipeline restored (the most measurement-stable
// attn structure: 43.2 +/- 0.03 us across 4 dispatches in R0) merged with all
// compatible post-R0 wins: swapped-QK^T cvt_pk softmax, XCD-grouped block
// decode, raw v_exp_f32, rcp epilogue, setprio on MFMA clusters.  Ks[3] +
// Vt[2] + Ps[4] = 56 KB -> 2 blocks/CU; plain __syncthreads (the stable
// variant's sync discipline).
// ---------------------------------------------------------------------------
__global__ __launch_bounds__(256, 2) void attn_flash(const unsigned short* __restrict__ Qb,
                                                     const unsigned short* __restrict__ Kb,
                                                     const unsigned short* __restrict__ Vtg,
                                                     _Float16* __restrict__ AO) {
    __shared__ __align__(16) unsigned short Ks[3][64 * 64];
    __shared__ __align__(16) unsigned short Vt[2][64 * 64];
    __shared__ __align__(16) unsigned short Ps[4][32 * 64];

    const int t    = threadIdx.x;
    const int lane = t & 63;
    const int w    = t >> 6;
    const int ln   = lane & 15;
    const int qd   = lane >> 4;

    // XCD-grouping decode: 512 blocks = 8 xcd * 8 hb-slots * 8 bq.
    const int lin  = blockIdx.x;
    const int slot = lin >> 3;
    const int hb   = (lin & 7) + 8 * (slot & 7);   // 0..63 = b*16+h
    const int bq   = slot >> 3;                    // 0..7
    const int h    = hb & 15;
    const int b    = hb >> 4;

    const size_t base = (size_t)(b * HH + h) * NN * DD;
    const char* Kc = (const char*)(Kb + base);
    const char* Vc = (const char*)(Vtg + base);
    const int xorc = ((lane & 7) ^ (lane >> 3)) * 16;
    const int r8   = lane >> 3;
    const int wrow = w * 16;

    bf16x8 qf[2][2];
    #pragma unroll
    for (int g = 0; g < 2; g++) {
        const unsigned short* qp = Qb + base +
            (size_t)(bq * 128 + w * 32 + g * 16 + ln) * DD + qd * 8;
        qf[g][0] = *(const bf16x8*)qp;
        qf[g][1] = *(const bf16x8*)(qp + 32);
    }

    f32x4 o[2][5];
    #pragma unroll
    for (int g = 0; g < 2; g++)
        #pragma unroll
        for (int x = 0; x < 5; x++) o[g][x] = (f32x4){0.f, 0.f, 0.f, 0.f};

    bf16x8 onesf;
    #pragma unroll
    for (int x = 0; x < 8; x++) onesf[x] = (short)0x3F80;  // bf16 1.0

    // prologue: stage K0,K1,K2 and V0,V1
    #pragma unroll
    for (int tile = 0; tile < 3; tile++)
        #pragma unroll
        for (int c = 0; c < 2; c++) {
            int rr = wrow + c * 8 + r8;
            ldg_lds16(Kc + (size_t)(tile * 64 + rr) * 128 + xorc,
                      &Ks[tile][(wrow + c * 8) * 64]);
        }
    #pragma unroll
    for (int tile = 0; tile < 2; tile++)
        #pragma unroll
        for (int c = 0; c < 2; c++) {
            int rr = wrow + c * 8 + r8;
            ldg_lds16(Vc + (size_t)rr * 2048 + (size_t)tile * 128 + xorc,
                      &Vt[tile][(wrow + c * 8) * 64]);
        }
    __syncthreads();

    f32x4 scur[2][4];
    {
        const unsigned short* KsB = Ks[0];
        #pragma unroll
        for (int j = 0; j < 4; j++) {
            bf16x8 k0f = *(const bf16x8*)&KsB[(ln + 16 * j) * 64 + ((qd ^ (ln & 7)) * 8)];
            bf16x8 k1f = *(const bf16x8*)&KsB[(ln + 16 * j) * 64 + (((4 + qd) ^ (ln & 7)) * 8)];
            #pragma unroll
            for (int g = 0; g < 2; g++) {
                f32x4 sj = {0.f, 0.f, 0.f, 0.f};
                sj = __builtin_amdgcn_mfma_f32_16x16x32_bf16(k0f, qf[g][0], sj, 0, 0, 0);
                sj = __builtin_amdgcn_mfma_f32_16x16x32_bf16(k1f, qf[g][1], sj, 0, 0, 0);
                scur[g][j] = sj;
            }
        }
    }

    const float C1 = 1.44269504f;
    const float C0 = -16.0f * 1.44269504f;
    const int swp = 2 * (ln & 7);
    unsigned short* PsB = &Ps[w][0];

    #pragma unroll
    for (int tt = 0; tt < 16; tt++) {
        // (a) S^T_{t+1} (from K staged 2 iterations ago — no wait needed)
        f32x4 snext[2][4];
        if (tt < 15) {
            const unsigned short* KsB = Ks[(tt + 1) % 3];
            __builtin_amdgcn_s_setprio(1);
            #pragma unroll
            for (int j = 0; j < 4; j++) {
                bf16x8 k0f = *(const bf16x8*)&KsB[(ln + 16 * j) * 64 + ((qd ^ (ln & 7)) * 8)];
                bf16x8 k1f = *(const bf16x8*)&KsB[(ln + 16 * j) * 64 + (((4 + qd) ^ (ln & 7)) * 8)];
                #pragma unroll
                for (int g = 0; g < 2; g++) {
                    f32x4 sj = {0.f, 0.f, 0.f, 0.f};
                    sj = __builtin_amdgcn_mfma_f32_16x16x32_bf16(k0f, qf[g][0], sj, 0, 0, 0);
                    sj = __builtin_amdgcn_mfma_f32_16x16x32_bf16(k1f, qf[g][1], sj, 0, 0, 0);
                    snext[g][j] = sj;
                }
            }
            __builtin_amdgcn_s_setprio(0);
        }

        // (b) fixed-max softmax -> Ps (per-wave; cvt_pk + b64 stores)
        #pragma unroll
        for (int g = 0; g < 2; g++) {
            char* rowp = (char*)PsB + (g * 16 + ln) * 128;
            #pragma unroll
            for (int j = 0; j < 4; j++) {
                float p0, p1, p2, p3;
                float x0 = fmaf(scur[g][j][0], C1, C0);
                float x1 = fmaf(scur[g][j][1], C1, C0);
                float x2 = fmaf(scur[g][j][2], C1, C0);
                float x3 = fmaf(scur[g][j][3], C1, C0);
                asm("v_exp_f32 %0, %1" : "=v"(p0) : "v"(x0));
                asm("v_exp_f32 %0, %1" : "=v"(p1) : "v"(x1));
                asm("v_exp_f32 %0, %1" : "=v"(p2) : "v"(x2));
                asm("v_exp_f32 %0, %1" : "=v"(p3) : "v"(x3));
                unsigned int lo, hi;
                asm("v_cvt_pk_bf16_f32 %0, %1, %2" : "=v"(lo) : "v"(p0), "v"(p1));
                asm("v_cvt_pk_bf16_f32 %0, %1, %2" : "=v"(hi) : "v"(p2), "v"(p3));
                u32x2 pk; pk[0] = lo; pk[1] = hi;
                *(u32x2*)(rowp + (((4 * j + qd) ^ swp) * 8)) = pk;
            }
        }

        // (c) P frags + PV (+ l row via ones)
        {
            const unsigned short* VtB = Vt[tt & 1];
            bf16x8 pf[2][2];
            #pragma unroll
            for (int g = 0; g < 2; g++) {
                pf[g][0] = *(const bf16x8*)&PsB[(g * 16 + ln) * 64 + ((qd ^ (ln & 7)) * 8)];
                pf[g][1] = *(const bf16x8*)&PsB[(g * 16 + ln) * 64 + (((4 + qd) ^ (ln & 7)) * 8)];
            }
            __builtin_amdgcn_s_setprio(1);
            #pragma unroll
            for (int j = 0; j < 4; j++) {
                bf16x8 v0f = *(const bf16x8*)&VtB[(ln + 16 * j) * 64 + ((qd ^ (ln & 7)) * 8)];
                bf16x8 v1f = *(const bf16x8*)&VtB[(ln + 16 * j) * 64 + (((4 + qd) ^ (ln & 7)) * 8)];
                #pragma unroll
                for (int g = 0; g < 2; g++) {
                    o[g][j] = __builtin_amdgcn_mfma_f32_16x16x32_bf16(pf[g][0], v0f, o[g][j], 0, 0, 0);
                    o[g][j] = __builtin_amdgcn_mfma_f32_16x16x32_bf16(pf[g][1], v1f, o[g][j], 0, 0, 0);
                }
            }
            #pragma unroll
            for (int g = 0; g < 2; g++) {
                o[g][4] = __builtin_amdgcn_mfma_f32_16x16x32_bf16(pf[g][0], onesf, o[g][4], 0, 0, 0);
                o[g][4] = __builtin_amdgcn_mfma_f32_16x16x32_bf16(pf[g][1], onesf, o[g][4], 0, 0, 0);
            }
            __builtin_amdgcn_s_setprio(0);
        }

        // (d) barrier (drains staging loads per compiler semantics)
        __syncthreads();

        // (e) stage K(tt+3) -> Ks[tt%3], V(tt+2) -> Vt[tt&1]
        if (tt <= 12) {
            int tile = tt + 3;
            #pragma unroll
            for (int c = 0; c < 2; c++) {
                int rr = wrow + c * 8 + r8;
                ldg_lds16(Kc + (size_t)(tile * 64 + rr) * 128 + xorc,
                          &Ks[tt % 3][(wrow + c * 8) * 64]);
            }
        }
        if (tt <= 13) {
            int tile = tt + 2;
            #pragma unroll
            for (int c = 0; c < 2; c++) {
                int rr = wrow + c * 8 + r8;
                ldg_lds16(Vc + (size_t)rr * 2048 + (size_t)tile * 128 + xorc,
                          &Vt[tt & 1][(wrow + c * 8) * 64]);
            }
        }

        #pragma unroll
        for (int g = 0; g < 2; g++)
            #pragma unroll
            for (int j = 0; j < 4; j++) scur[g][j] = snext[g][j];
    }

    #pragma unroll
    for (int g = 0; g < 2; g++)
        #pragma unroll
        for (int r = 0; r < 4; r++) {
            float inv = __builtin_amdgcn_rcpf(o[g][4][r]);
            int q = bq * 128 + w * 32 + g * 16 + qd * 4 + r;
            _Float16* op = AO + (((size_t)b * NN + q) * HH + h) * DD + ln;
            op[0]  = (_Float16)(o[g][0][r] * inv);
            op[16] = (_Float16)(o[g][1][r] * inv);
            op[32] = (_Float16)(o[g][2][r] * inv);
            op[48] = (_Float16)(o[g][3][r] * inv);
        }
}

// ---------------------------------------------------------------------------
// Proj GEMM v2 (unchanged from R9): 128x128, BK=32, 4-slot deep pipeline,
// grid 8x32 = 256 blocks = 1/CU.
// ---------------------------------------------------------------------------
__global__ __launch_bounds__(512, 2) void proj_mfma(const _Float16* __restrict__ Ah,
                                                    const _Float16* __restrict__ Bt,
                                                    const float* __restrict__ bias,
                                                    float* __restrict__ out) {
    __shared__ __align__(16) _Float16 LA[4][128 * 32];   // 8 KB / slot
    __shared__ __align__(16) _Float16 LB[4][128 * 32];

    const int t    = threadIdx.x;
    const int lane = t & 63;
    const int w    = t >> 6;
    const int ln   = lane & 15, qd = lane >> 4;
    const int n0   = blockIdx.x * 128;
    const int m0   = blockIdx.y * 128;
    const int wm   = (w >> 2) * 64;
    const int wn   = (w & 3) * 32;

    const int L  = t >> 3, hc = (t & 7) ^ (L & 7);
    const int row = 2 * L + (hc >> 2), co = (hc & 3) * 16;
    const char* gA = (const char*)Ah;
    const char* gB = (const char*)Bt;
    const size_t aof = (size_t)(m0 + row) * 2048 + co;
    const size_t bof = (size_t)(n0 + row) * 2048 + co;
    const int ld = (w * 64) * 8;

#define PSTAGE(kk, SLOT) { ldg_lds16(gA + aof + (size_t)(kk) * 64, &LA[SLOT][ld]); \
                           ldg_lds16(gB + bof + (size_t)(kk) * 64, &LB[SLOT][ld]); }

    PSTAGE(0, 0); PSTAGE(1, 1); PSTAGE(2, 2);
    wvm4();
    barx();

    f32x4 acc[4][2];
    #pragma unroll
    for (int i = 0; i < 4; i++)
        #pragma unroll
        for (int j = 0; j < 2; j++) acc[i][j] = (f32x4){0.f, 0.f, 0.f, 0.f};

    auto frag = [&](const _Float16* Lb, int r, int c) -> f16x8 {
        int idx = ((r >> 1) << 6) + ((((((r & 1) << 2) | c)) ^ ((r >> 1) & 7)) << 3);
        return *(const f16x8*)&Lb[idx];
    };

#define PTILE(kk, SLOT, STG, WAITFN) {                                              \
    const _Float16* Ab = LA[SLOT];                                                  \
    const _Float16* Bb = LB[SLOT];                                                  \
    f16x8 af[4], bf[2];                                                             \
    _Pragma("unroll") for (int i = 0; i < 4; i++) af[i] = frag(Ab, wm + i * 16 + ln, qd); \
    _Pragma("unroll") for (int j = 0; j < 2; j++) bf[j] = frag(Bb, wn + j * 16 + ln, qd); \
    if (STG) PSTAGE((kk) + 3, ((kk) + 3) & 3);                                      \
    WAITFN();                                                                       \
    barx(); wlg0();                                                                 \
    __builtin_amdgcn_s_setprio(1);                                                  \
    _Pragma("unroll") for (int i = 0; i < 4; i++)                                   \
        _Pragma("unroll") for (int j = 0; j < 2; j++)                               \
            acc[i][j] = __builtin_amdgcn_mfma_f32_16x16x32_f16(af[i], bf[j], acc[i][j], 0, 0, 0); \
    __builtin_amdgcn_s_setprio(0);                                                  \
    barx();                                                                         \
}

    for (int k = 0; k < 28; k += 4) {
        PTILE(k + 0, 0, 1, wvm4);
        PTILE(k + 1, 1, 1, wvm4);
        PTILE(k + 2, 2, 1, wvm4);
        PTILE(k + 3, 3, 1, wvm4);
    }
    PTILE(28, 0, 1, wvm4);   // stages tile 31
    PTILE(29, 1, 0, wvm2);
    PTILE(30, 2, 0, wvm0);
    PTILE(31, 3, 0, wnone);

#undef PTILE
#undef PSTAGE

    const float bc0 = bias[n0 + wn + ln];
    const float bc1 = bias[n0 + wn + 16 + ln];
    #pragma unroll
    for (int i = 0; i < 4; i++) {
        #pragma unroll
        for (int reg = 0; reg < 4; reg++) {
            int rowo = m0 + wm + i * 16 + qd * 4 + reg;
            float* op = out + (size_t)rowo * 1024 + n0 + wn + ln;
            op[0]  = acc[i][0][reg] + bc0;
            op[16] = acc[i][1][reg] + bc1;
        }
    }
}

// ---------------------------------------------------------------------------
extern "C" void kernel_launch(void* const* d_in, const int* in_sizes, int n_in,
                              void* d_out, int out_size, void* d_ws, size_t ws_size,
                              hipStream_t stream) {
    const float* x      = (const float*)d_in[0];
    const float* w_qkv  = (const float*)d_in[1];
    const float* b_qkv  = (const float*)d_in[2];
    const float* w_proj = (const float*)d_in[3];
    const float* b_proj = (const float*)d_in[4];
    float* out = (float*)d_out;

    char* ws = (char*)d_ws;
    _Float16* Xh   = (_Float16*)(ws);                         // 8 MB
    _Float16* Wqt  = (_Float16*)(ws + (8u << 20));            // 6 MB
    _Float16* Wpt  = (_Float16*)(ws + (14u << 20));           // 2 MB
    unsigned short* Q  = (unsigned short*)(ws + (16u << 20)); // 8 MB (B,H,N,D) bf16, pre-scaled
    unsigned short* K  = (unsigned short*)(ws + (24u << 20)); // 8 MB (B,H,N,D)
    unsigned short* Vt = (unsigned short*)(ws + (32u << 20)); // 8 MB (B,H,D,N) transposed
    _Float16* AOh  = (_Float16*)(ws + (40u << 20));           // 8 MB
    float* cost    = (float*)(ws + (48u << 20));              // 128 KB
    float* sint    = (float*)(ws + (48u << 20) + (128u << 10));

    prep<<<5248, 256, 0, stream>>>(x, w_qkv, w_proj, Xh, Wqt, Wpt, cost, sint);
    qkv_mfma<<<dim3(12, 16), 512, 0, stream>>>(Xh, Wqt, b_qkv, cost, sint, Q, K, Vt);
    attn_flash<<<512, 256, 0, stream>>>(Q, K, Vt, AOh);
    proj_mfma<<<dim3(8, 32), 512, 0, stream>>>(AOh, Wpt, b_proj, out);
}